// Round 11
// baseline (58.231 us; speedup 1.0000x reference)
//
#include <hip/hip_runtime.h>

typedef __attribute__((ext_vector_type(8))) short short8;
typedef __attribute__((ext_vector_type(4))) float f32x4;
typedef __attribute__((ext_vector_type(4))) unsigned short ushort4_t;

#define NL 48
#define NB 16
#define NROWS (NL*NL*NB)   // 36864

// ---- workspace layout (float units) ----
#define HB_N     (NROWS*128/2)            // bf16 H: 2359296 float-slots
#define HB_OFF   0
#define W34T_OFF (HB_OFF + HB_N)          // bf16 [128n][256k] = 16384 floats
#define WD_OFF   (W34T_OFF + 16384)       // bf16 [384n][384k] = 73728 floats
#define X2_OFF   (WD_OFF + 73728)         // bf16 [768m][384k] = 147456 floats
#define VEC_N    (NL*NB*128)              // 98304
#define RA_OFF   (X2_OFF + 147456)
#define AJ_OFF   (RA_OFF + VEC_N)
#define AI_OFF   (AJ_OFF + VEC_N)
#define AD_OFF   (AI_OFF + VEC_N)
#define AB_OFF   (AD_OFF + VEC_N)
#define DGA_OFF  (AB_OFF + NB*128)
#define FLAG_OFF (DGA_OFF + NB*128)

__device__ __forceinline__ float silu_f(float x) { return x / (1.0f + __expf(-x)); }
__device__ __forceinline__ unsigned short f2bf(float x) {
  union { float f; unsigned u; } v; v.f = x;
  unsigned r = v.u + 0x7fffu + ((v.u >> 16) & 1u);
  return (unsigned short)(r >> 16);
}
__device__ __forceinline__ float bf2f(unsigned short h) {
  union { unsigned u; float f; } v; v.u = ((unsigned)h) << 16; return v.f;
}

// ---------- kernel A (MFMA) + embedded prep ----------
// blocks 0..575: Hb = bf16(silu(BN(T)@w1+b1)) (w1 transposed in-block)
// blocks 576..583: w34t ; 584..619: wd ; 620: mask-dtype detect
__global__ __launch_bounds__(256) void kA(const float* __restrict__ T,
    const float* __restrict__ rmean, const float* __restrict__ rvar,
    const float* __restrict__ bw, const float* __restrict__ bb,
    const float* __restrict__ w1, const float* __restrict__ b1,
    const float* __restrict__ w2, const unsigned char* __restrict__ mb,
    unsigned short* __restrict__ Hb, unsigned short* __restrict__ w34t,
    unsigned short* __restrict__ wd, int* __restrict__ flag)
{
  __shared__ __align__(16) char SM[49152];
  __shared__ int any;
  char* XDS = SM;            // [64 r][128 k] bf16 swizzled (16 KB)
  char* WDS = SM + 16384;    // [128 n][128 k] bf16 swizzled (32 KB)
  float* tt = (float*)SM;    // prep transpose tile (prep blocks only)
  int tid = threadIdx.x;
  int blk = blockIdx.x;

  if (blk >= 576) {
    int pb = blk - 576;
    if (pb < 8) {            // w34t[n][k]: k<128 -> w2 slice4, k>=128 -> slice3
      int k0 = (pb & 3)*64, n0 = (pb >> 2)*64;
      #pragma unroll
      for (int it = 0; it < 16; ++it) { int f = it*256+tid; int kk=f>>6, nn=f&63;
        int k = k0+kk; int slice = (k < 128) ? 4 : 3;
        tt[kk*65+nn] = w2[slice*16384 + (k&127)*128 + n0+nn]; }
      __syncthreads();
      #pragma unroll
      for (int it = 0; it < 16; ++it) { int f = it*256+tid; int nn=f>>6, kk=f&63;
        w34t[(n0+nn)*256 + k0+kk] = f2bf(tt[kk*65+nn]); }
    } else if (pb < 44) {    // wd [384n][384k]
      int q = pb-8; int k0 = (q%6)*64, n0 = (q/6)*64;
      int nq = n0 >> 7, kq = k0 >> 7;
      int slice;
      {
        const int sl_aj[3] = {1,9,10};
        const int sl_ai[3] = {2,13,12};
        const int sl_ad[3] = {0,5,6};
        slice = (nq==0) ? sl_aj[kq] : (nq==1) ? sl_ai[kq] : sl_ad[kq];
      }
      int nb = n0 & 127;
      #pragma unroll
      for (int it = 0; it < 16; ++it) { int f = it*256+tid; int kk=f>>6, nn=f&63;
        tt[kk*65+nn] = w2[slice*16384 + ((k0&127)+kk)*128 + nb+nn]; }
      __syncthreads();
      #pragma unroll
      for (int it = 0; it < 16; ++it) { int f = it*256+tid; int nn=f>>6, kk=f&63;
        wd[(n0+nn)*384 + k0+kk] = f2bf(tt[kk*65+nn]); }
    } else {                 // detect mask byte-stride
      if (tid == 0) any = 0;
      __syncthreads();
      int acc = 0;
      #pragma unroll
      for (int k2 = 0; k2 < 12; ++k2) {
        uchar4 v = ((const uchar4*)mb)[tid + k2*256];
        acc |= v.y | v.z | v.w;
      }
      if (acc) atomicOr(&any, 1);
      __syncthreads();
      if (tid == 0) *flag = any ? 1 : 4;
    }
    return;
  }

  int m0 = blk * 64;
  int cbase = (tid & 31) * 4;
  float scr[4], shr[4];
  #pragma unroll
  for (int u = 0; u < 4; ++u) {
    float s = bw[cbase+u] * rsqrtf(rvar[cbase+u] + 1e-5f);
    scr[u] = s; shr[u] = bb[cbase+u] - rmean[cbase+u] * s;
  }
  // stage X (BN + bf16), nontemporal read of T (touched once)
  #pragma unroll
  for (int t = 0; t < 8; ++t) {
    int f = t*256 + tid;
    int r = f >> 5, c4 = f & 31;
    f32x4 v = __builtin_nontemporal_load((const f32x4*)&T[(m0 + r)*128 + c4*4]);
    ushort4_t p;
    p.x = f2bf(v.x*scr[0] + shr[0]); p.y = f2bf(v.y*scr[1] + shr[1]);
    p.z = f2bf(v.z*scr[2] + shr[2]); p.w = f2bf(v.w*scr[3] + shr[3]);
    *(ushort4_t*)(XDS + r*256 + ((c4*8) ^ ((r & 7) << 4))) = p;
  }
  // stage W1^T: WDS[n][k] from w1[k][n]
  {
    int n = tid & 127, ch = (tid >> 7) * 8;
    #pragma unroll
    for (int cc = 0; cc < 8; ++cc) {
      int c = ch + cc;
      short8 v;
      #pragma unroll
      for (int j = 0; j < 8; ++j)
        ((unsigned short*)&v)[j] = f2bf(w1[(c*8 + j)*128 + n]);
      *(short8*)(WDS + n*256 + ((c*16) ^ ((n & 7) << 4))) = v;
    }
  }
  __syncthreads();

  int wave = tid >> 6, lane = tid & 63;
  int ln = lane & 15, lg = lane >> 4;
  int rw = (wave >> 1) * 32, cw = (wave & 1) * 64;
  int swz = (ln & 7) << 4;
  f32x4 acc[2][4];
  #pragma unroll
  for (int mt = 0; mt < 2; ++mt)
    #pragma unroll
    for (int nt = 0; nt < 4; ++nt) acc[mt][nt] = (f32x4){0.f,0.f,0.f,0.f};

  #pragma unroll
  for (int ks = 0; ks < 4; ++ks) {
    int kb = ks*64 + lg*16;
    short8 a[2], b[4];
    #pragma unroll
    for (int mt = 0; mt < 2; ++mt)
      a[mt] = *(const short8*)(XDS + (rw + mt*16 + ln)*256 + (kb ^ swz));
    #pragma unroll
    for (int nt = 0; nt < 4; ++nt)
      b[nt] = *(const short8*)(WDS + (cw + nt*16 + ln)*256 + (kb ^ swz));
    #pragma unroll
    for (int mt = 0; mt < 2; ++mt)
      #pragma unroll
      for (int nt = 0; nt < 4; ++nt)
        acc[mt][nt] = __builtin_amdgcn_mfma_f32_16x16x32_bf16(a[mt], b[nt], acc[mt][nt], 0, 0, 0);
  }
  float b1v[4];
  #pragma unroll
  for (int nt = 0; nt < 4; ++nt) b1v[nt] = b1[cw + nt*16 + ln];
  #pragma unroll
  for (int mt = 0; mt < 2; ++mt)
    #pragma unroll
    for (int q = 0; q < 4; ++q) {
      int m = m0 + rw + mt*16 + 4*lg + q;
      #pragma unroll
      for (int nt = 0; nt < 4; ++nt) {
        float x = acc[mt][nt][q] + b1v[nt];
        Hb[m*128 + cw + nt*16 + ln] = f2bf(silu_f(x));
      }
    }
}

// ---------- kAgg: masked row/col sums, 256 thr, q-loop split + LDS combine ----------
__global__ __launch_bounds__(256) void kAgg(const unsigned short* __restrict__ Hb,
    const unsigned char* __restrict__ mb, const int* __restrict__ flag,
    float* __restrict__ ra, unsigned short* __restrict__ X2)
{
  __shared__ float part[2][64][2];
  int p = blockIdx.x, b = blockIdx.y;
  int tid = threadIdx.x;
  int s = *flag;
  int qh   = tid >> 7;         // q-half: 0 -> q<24, 1 -> q>=24
  int half = (tid >> 6) & 1;   // 0: col (sum over axis1), 1: row (sum over axis0)
  int t = tid & 63;            // e-pair: e = 2t, 2t+1
  float a0 = 0.f, a1 = 0.f;
  #pragma unroll 12
  for (int qq = 0; qq < 24; ++qq) {
    int q = qh*24 + qq;
    int mi = half ? ((q*NL + p)*NB + b) : ((p*NL + q)*NB + b);
    float mv = (float)mb[mi*s];
    unsigned u = *(const unsigned*)(Hb + mi*128 + 2*t);
    a0 += mv * bf2f((unsigned short)(u & 0xffffu));
    a1 += mv * bf2f((unsigned short)(u >> 16));
  }
  if (qh) { part[half][t][0] = a0; part[half][t][1] = a1; }
  __syncthreads();
  if (!qh) {
    a0 = (a0 + part[half][t][0]) * (1.0f/60.0f);
    a1 = (a1 + part[half][t][1]) * (1.0f/60.0f);
    int ix = p*NB + b;
    unsigned pk = ((unsigned)f2bf(a1) << 16) | (unsigned)f2bf(a0);
    if (half) {  // row_agg -> ra + X2 chunk1
      *(float2*)(ra + ix*128 + 2*t) = make_float2(a0, a1);
      *(unsigned*)(X2 + ix*384 + 128 + 2*t) = pk;
    } else {     // col_agg -> X2 chunk2; diag -> X2 chunk0
      *(unsigned*)(X2 + ix*384 + 256 + 2*t) = pk;
      unsigned d = *(const unsigned*)(Hb + ((p*NL + p)*NB + b)*128 + 2*t);
      *(unsigned*)(X2 + ix*384 + 2*t) = d;
    }
  }
}

// ---------- kDm: y<3 MFMA [Aj|Ai|Adg] = X2 @ Wd^T ; y==3: Abase/Dga ----------
__global__ __launch_bounds__(256) void kDm(const unsigned short* __restrict__ X2,
    const unsigned short* __restrict__ wd,
    const unsigned short* __restrict__ Hb, const unsigned char* __restrict__ mb,
    const int* __restrict__ flag, const float* __restrict__ ra,
    const float* __restrict__ w2, const float* __restrict__ b2,
    float* __restrict__ Aj, float* __restrict__ Ai, float* __restrict__ Adg,
    float* __restrict__ Ab, float* __restrict__ Dga)
{
  int tid = threadIdx.x;
  if (blockIdx.y == 3) {
    int b = blockIdx.x;
    __shared__ float aas[128], dgs[128];
    int e = tid & 127;
    if (tid < 128) {
      int s = *flag;
      float aa = 0.f, dg = 0.f;
      #pragma unroll 8
      for (int p = 0; p < NL; ++p) {
        aa += ra[(p*NB + b)*128 + e];
        int mi = (p*NL + p)*NB + b;
        dg += (float)mb[mi*s] * bf2f(Hb[mi*128 + e]);
      }
      aas[e] = aa * (1.0f/60.0f);
      dgs[e] = dg * (1.0f/60.0f);
    }
    __syncthreads();
    if (tid < 128) {
      float ab = b2[e];
      #pragma unroll 8
      for (int k = 0; k < 128; ++k) {
        int o = k*128 + e;
        ab += dgs[k]*w2[8*16384 + o] + aas[k]*(w2[11*16384 + o] + w2[14*16384 + o]);
      }
      Ab[b*128 + e] = ab;
    } else {
      float dga = 0.f;
      #pragma unroll 8
      for (int k = 0; k < 128; ++k)
        dga += dgs[k]*w2[7*16384 + k*128 + e];
      Dga[b*128 + e] = dga;
    }
    return;
  }
  if (blockIdx.x >= 12) return;

  __shared__ __align__(16) char ADS[64*256];
  __shared__ __align__(16) char BDS[128*256];
  int m0 = blockIdx.x * 64;
  int n0 = blockIdx.y * 128;

  int wave = tid >> 6, lane = tid & 63;
  int ln = lane & 15, lg = lane >> 4;
  int rw = (wave >> 1) * 32, cw = (wave & 1) * 64;
  int swzk = (ln & 7) << 4;
  f32x4 acc[2][4];
  #pragma unroll
  for (int mt = 0; mt < 2; ++mt)
    #pragma unroll
    for (int nt = 0; nt < 4; ++nt) acc[mt][nt] = (f32x4){0.f,0.f,0.f,0.f};

  for (int kc = 0; kc < 3; ++kc) {
    if (kc) __syncthreads();
    #pragma unroll
    for (int t = 0; t < 4; ++t) {
      int f = t*256 + tid;
      int r = f >> 4, c16 = f & 15;
      short8 v = *(const short8*)(X2 + (m0 + r)*384 + kc*128 + c16*8);
      *(short8*)(ADS + r*256 + ((c16*16) ^ ((r & 7) << 4))) = v;
    }
    #pragma unroll
    for (int t = 0; t < 8; ++t) {
      int f = t*256 + tid;
      int r = f >> 4, c16 = f & 15;
      short8 v = *(const short8*)(wd + (n0 + r)*384 + kc*128 + c16*8);
      *(short8*)(BDS + r*256 + ((c16*16) ^ ((r & 7) << 4))) = v;
    }
    __syncthreads();
    #pragma unroll
    for (int ks = 0; ks < 4; ++ks) {
      int kb = ks*64 + lg*16;
      short8 a[2], b[4];
      #pragma unroll
      for (int mt = 0; mt < 2; ++mt)
        a[mt] = *(const short8*)(ADS + (rw + mt*16 + ln)*256 + (kb ^ swzk));
      #pragma unroll
      for (int nt = 0; nt < 4; ++nt)
        b[nt] = *(const short8*)(BDS + (cw + nt*16 + ln)*256 + (kb ^ swzk));
      #pragma unroll
      for (int mt = 0; mt < 2; ++mt)
        #pragma unroll
        for (int nt = 0; nt < 4; ++nt)
          acc[mt][nt] = __builtin_amdgcn_mfma_f32_16x16x32_bf16(a[mt], b[nt], acc[mt][nt], 0, 0, 0);
    }
  }
  float* outp = (blockIdx.y == 0) ? Aj : (blockIdx.y == 1) ? Ai : Adg;
  #pragma unroll
  for (int mt = 0; mt < 2; ++mt)
    #pragma unroll
    for (int q = 0; q < 4; ++q) {
      int row = m0 + rw + mt*16 + 4*lg + q;
      #pragma unroll
      for (int nt = 0; nt < 4; ++nt)
        outp[row*128 + cw + nt*16 + ln] = acc[mt][nt][q];
    }
}

// ---------- kernel E (MFMA): out = Hd@W4 + Ht@W3 + additive ----------
// LDS = A-half only (16 KB -> 8 blocks/CU); B-fragments DIRECT from global
// (w34t is 64 KB, identical across all blocks -> L2-hot; per-wave pattern
// covers 16 full cachelines per load). XCD-aware block swizzle.
__global__ __launch_bounds__(256) void kE(const unsigned short* __restrict__ Hb,
    const unsigned short* __restrict__ w34t,
    const float* __restrict__ Aj, const float* __restrict__ Ai,
    const float* __restrict__ Adg, const float* __restrict__ Ab,
    const float* __restrict__ Dga,
    float* __restrict__ out)
{
  __shared__ __align__(16) char ADS[64*256];   // 16 KB
  int tid = threadIdx.x;
  // XCD swizzle: 576 blocks = 8 XCDs x 72; XCD x owns bi in [x*6, x*6+6)
  int x = blockIdx.x & 7, sl = blockIdx.x >> 3;
  int bi = x*6 + sl/12;
  int j0 = (sl % 12) * 4;
  int m0 = (bi*NL + j0) * NB;

  int wave = tid >> 6, lane = tid & 63;
  int ln = lane & 15, lg = lane >> 4;
  int rw = (wave >> 1) * 32, cw = (wave & 1) * 64;
  int swz = (ln & 7) << 4;
  f32x4 acc[2][4];
  #pragma unroll
  for (int mt = 0; mt < 2; ++mt)
    #pragma unroll
    for (int nt = 0; nt < 4; ++nt) acc[mt][nt] = (f32x4){0.f,0.f,0.f,0.f};

  #pragma unroll
  for (int half = 0; half < 2; ++half) {
    if (half) __syncthreads();     // protect ADS reuse
    // stage A half: half0 = Hd rows (contiguous), half1 = Ht rows
    #pragma unroll
    for (int t = 0; t < 4; ++t) {
      int f = t*256 + tid;
      int r = f >> 4, c16 = f & 15;
      int srcrow = (half == 0) ? (m0 + r) : (((j0 + (r >> 4))*NL + bi)*NB + (r & 15));
      short8 v = *(const short8*)(Hb + srcrow*128 + c16*8);
      *(short8*)(ADS + r*256 + ((c16*16) ^ ((r & 7) << 4))) = v;
    }
    __syncthreads();
    #pragma unroll
    for (int ks = 0; ks < 4; ++ks) {
      int kb = ks*64 + lg*16;
      short8 a[2], b[4];
      #pragma unroll
      for (int mt = 0; mt < 2; ++mt)
        a[mt] = *(const short8*)(ADS + (rw + mt*16 + ln)*256 + (kb ^ swz));
      #pragma unroll
      for (int nt = 0; nt < 4; ++nt)
        b[nt] = *(const short8*)(w34t + (cw + nt*16 + ln)*256 + half*128 + ks*32 + lg*8);
      #pragma unroll
      for (int mt = 0; mt < 2; ++mt)
        #pragma unroll
        for (int nt = 0; nt < 4; ++nt)
          acc[mt][nt] = __builtin_amdgcn_mfma_f32_16x16x32_bf16(a[mt], b[nt], acc[mt][nt], 0, 0, 0);
    }
  }

  #pragma unroll
  for (int mt = 0; mt < 2; ++mt) {
    int tb = rw + mt*16;
    int jj = tb >> 4;
    int j = j0 + jj;
    bool isdiag = (bi == j);
    #pragma unroll
    for (int q = 0; q < 4; ++q) {
      int b = 4*lg + q;
      int m = (bi*NL + j)*NB + b;
      #pragma unroll
      for (int nt = 0; nt < 4; ++nt) {
        int n = cw + nt*16 + ln;
        float add = Aj[(j*NB + b)*128 + n] + Ai[(bi*NB + b)*128 + n] + Ab[b*128 + n];
        if (isdiag) add += Adg[(bi*NB + b)*128 + n] + Dga[b*128 + n];
        out[m*128 + n] = acc[mt][nt][q] + add;
      }
    }
  }
}

extern "C" void kernel_launch(void* const* d_in, const int* in_sizes, int n_in,
                              void* d_out, int out_size, void* d_ws, size_t ws_size,
                              hipStream_t stream) {
  (void)in_sizes; (void)n_in; (void)out_size; (void)ws_size;
  const float* T      = (const float*)d_in[0];
  const unsigned char* mask = (const unsigned char*)d_in[1];
  const float* rmean  = (const float*)d_in[2];
  const float* rvar   = (const float*)d_in[3];
  const float* bw     = (const float*)d_in[4];
  const float* bb     = (const float*)d_in[5];
  const float* w1     = (const float*)d_in[6];
  const float* b1     = (const float*)d_in[7];
  const float* w2     = (const float*)d_in[8];
  const float* b2     = (const float*)d_in[9];
  float* ws  = (float*)d_ws;
  float* out = (float*)d_out;

  unsigned short* Hb   = (unsigned short*)(ws + HB_OFF);
  unsigned short* w34t = (unsigned short*)(ws + W34T_OFF);
  unsigned short* wd   = (unsigned short*)(ws + WD_OFF);
  unsigned short* X2   = (unsigned short*)(ws + X2_OFF);
  float* ra   = ws + RA_OFF;
  float* Aj   = ws + AJ_OFF;
  float* Ai   = ws + AI_OFF;
  float* Adg  = ws + AD_OFF;
  float* Ab   = ws + AB_OFF;
  float* Dga  = ws + DGA_OFF;
  int*   flag = (int*)(ws + FLAG_OFF);

  kA<<<621, 256, 0, stream>>>(T, rmean, rvar, bw, bb, w1, b1, w2, mask,
                              Hb, w34t, wd, flag);
  kAgg<<<dim3(NL, NB), 256, 0, stream>>>(Hb, mask, flag, ra, X2);
  kDm<<<dim3(16, 4), 256, 0, stream>>>(X2, wd, Hb, mask, flag, ra, w2, b2,
                                       Aj, Ai, Adg, Ab, Dga);
  kE<<<NROWS/64, 256, 0, stream>>>(Hb, w34t, Aj, Ai, Adg, Ab, Dga, out);
}

// Round 12
// 51.484 us; speedup vs baseline: 1.1310x; 1.1310x over previous
//
#include <hip/hip_runtime.h>

typedef __attribute__((ext_vector_type(8))) short short8;
typedef __attribute__((ext_vector_type(4))) float f32x4;
typedef __attribute__((ext_vector_type(4))) unsigned short ushort4_t;

#define NL 48
#define NB 16
#define NROWS (NL*NL*NB)   // 36864

// ---- workspace layout (float units) ----
#define HB_N     (NROWS*128/2)            // bf16 H: 2359296 float-slots
#define HB_OFF   0
#define W34T_OFF (HB_OFF + HB_N)          // bf16 [128n][256k] = 16384 floats
#define WD_OFF   (W34T_OFF + 16384)       // bf16 [384n][384k] = 73728 floats
#define X2_OFF   (WD_OFF + 73728)         // bf16 [768m][384k] = 147456 floats
#define VEC_N    (NL*NB*128)              // 98304
#define RA_OFF   (X2_OFF + 147456)
#define AJ_OFF   (RA_OFF + VEC_N)
#define AI_OFF   (AJ_OFF + VEC_N)
#define AD_OFF   (AI_OFF + VEC_N)
#define AB_OFF   (AD_OFF + VEC_N)
#define DGA_OFF  (AB_OFF + NB*128)
#define FLAG_OFF (DGA_OFF + NB*128)

__device__ __forceinline__ float silu_f(float x) { return x / (1.0f + __expf(-x)); }
__device__ __forceinline__ unsigned short f2bf(float x) {
  union { float f; unsigned u; } v; v.f = x;
  unsigned r = v.u + 0x7fffu + ((v.u >> 16) & 1u);
  return (unsigned short)(r >> 16);
}
__device__ __forceinline__ float bf2f(unsigned short h) {
  union { unsigned u; float f; } v; v.u = ((unsigned)h) << 16; return v.f;
}

// ---------- kernel A (MFMA) + embedded prep ----------
// blocks 0..575: Hb = bf16(silu(BN(T)@w1+b1)) (w1 transposed in-block)
// blocks 576..583: w34t ; 584..619: wd ; 620: mask-dtype detect
__global__ __launch_bounds__(256) void kA(const float* __restrict__ T,
    const float* __restrict__ rmean, const float* __restrict__ rvar,
    const float* __restrict__ bw, const float* __restrict__ bb,
    const float* __restrict__ w1, const float* __restrict__ b1,
    const float* __restrict__ w2, const unsigned char* __restrict__ mb,
    unsigned short* __restrict__ Hb, unsigned short* __restrict__ w34t,
    unsigned short* __restrict__ wd, int* __restrict__ flag)
{
  __shared__ __align__(16) char SM[49152];
  __shared__ int any;
  char* XDS = SM;            // [64 r][128 k] bf16 swizzled (16 KB)
  char* WDS = SM + 16384;    // [128 n][128 k] bf16 swizzled (32 KB)
  float* tt = (float*)SM;    // prep transpose tile (prep blocks only)
  int tid = threadIdx.x;
  int blk = blockIdx.x;

  if (blk >= 576) {
    int pb = blk - 576;
    if (pb < 8) {            // w34t[n][k]: k<128 -> w2 slice4, k>=128 -> slice3
      int k0 = (pb & 3)*64, n0 = (pb >> 2)*64;
      #pragma unroll
      for (int it = 0; it < 16; ++it) { int f = it*256+tid; int kk=f>>6, nn=f&63;
        int k = k0+kk; int slice = (k < 128) ? 4 : 3;
        tt[kk*65+nn] = w2[slice*16384 + (k&127)*128 + n0+nn]; }
      __syncthreads();
      #pragma unroll
      for (int it = 0; it < 16; ++it) { int f = it*256+tid; int nn=f>>6, kk=f&63;
        w34t[(n0+nn)*256 + k0+kk] = f2bf(tt[kk*65+nn]); }
    } else if (pb < 44) {    // wd [384n][384k]
      int q = pb-8; int k0 = (q%6)*64, n0 = (q/6)*64;
      int nq = n0 >> 7, kq = k0 >> 7;
      int slice;
      {
        const int sl_aj[3] = {1,9,10};
        const int sl_ai[3] = {2,13,12};
        const int sl_ad[3] = {0,5,6};
        slice = (nq==0) ? sl_aj[kq] : (nq==1) ? sl_ai[kq] : sl_ad[kq];
      }
      int nb = n0 & 127;
      #pragma unroll
      for (int it = 0; it < 16; ++it) { int f = it*256+tid; int kk=f>>6, nn=f&63;
        tt[kk*65+nn] = w2[slice*16384 + ((k0&127)+kk)*128 + nb+nn]; }
      __syncthreads();
      #pragma unroll
      for (int it = 0; it < 16; ++it) { int f = it*256+tid; int nn=f>>6, kk=f&63;
        wd[(n0+nn)*384 + k0+kk] = f2bf(tt[kk*65+nn]); }
    } else {                 // detect mask byte-stride
      if (tid == 0) any = 0;
      __syncthreads();
      int acc = 0;
      #pragma unroll
      for (int k2 = 0; k2 < 12; ++k2) {
        uchar4 v = ((const uchar4*)mb)[tid + k2*256];
        acc |= v.y | v.z | v.w;
      }
      if (acc) atomicOr(&any, 1);
      __syncthreads();
      if (tid == 0) *flag = any ? 1 : 4;
    }
    return;
  }

  int m0 = blk * 64;
  // per-thread BN constants for its 4 fixed columns
  int cbase = (tid & 31) * 4;
  float scr[4], shr[4];
  #pragma unroll
  for (int u = 0; u < 4; ++u) {
    float s = bw[cbase+u] * rsqrtf(rvar[cbase+u] + 1e-5f);
    scr[u] = s; shr[u] = bb[cbase+u] - rmean[cbase+u] * s;
  }
  // stage X (BN + bf16)
  #pragma unroll
  for (int t = 0; t < 8; ++t) {
    int f = t*256 + tid;
    int r = f >> 5, c4 = f & 31;
    f32x4 v = __builtin_nontemporal_load((const f32x4*)&T[(m0 + r)*128 + c4*4]);
    ushort4_t p;
    p.x = f2bf(v.x*scr[0] + shr[0]); p.y = f2bf(v.y*scr[1] + shr[1]);
    p.z = f2bf(v.z*scr[2] + shr[2]); p.w = f2bf(v.w*scr[3] + shr[3]);
    *(ushort4_t*)(XDS + r*256 + ((c4*8) ^ ((r & 7) << 4))) = p;
  }
  // stage W1^T: WDS[n][k] from w1[k][n] (n-coalesced per wave, swizzled b128 writes)
  {
    int n = tid & 127, ch = (tid >> 7) * 8;
    #pragma unroll
    for (int cc = 0; cc < 8; ++cc) {
      int c = ch + cc;
      short8 v;
      #pragma unroll
      for (int j = 0; j < 8; ++j)
        ((unsigned short*)&v)[j] = f2bf(w1[(c*8 + j)*128 + n]);
      *(short8*)(WDS + n*256 + ((c*16) ^ ((n & 7) << 4))) = v;
    }
  }
  __syncthreads();

  int wave = tid >> 6, lane = tid & 63;
  int ln = lane & 15, lg = lane >> 4;
  int rw = (wave >> 1) * 32, cw = (wave & 1) * 64;
  int swz = (ln & 7) << 4;
  f32x4 acc[2][4];
  #pragma unroll
  for (int mt = 0; mt < 2; ++mt)
    #pragma unroll
    for (int nt = 0; nt < 4; ++nt) acc[mt][nt] = (f32x4){0.f,0.f,0.f,0.f};

  #pragma unroll
  for (int ks = 0; ks < 4; ++ks) {
    int kb = ks*64 + lg*16;
    short8 a[2], b[4];
    #pragma unroll
    for (int mt = 0; mt < 2; ++mt)
      a[mt] = *(const short8*)(XDS + (rw + mt*16 + ln)*256 + (kb ^ swz));
    #pragma unroll
    for (int nt = 0; nt < 4; ++nt)
      b[nt] = *(const short8*)(WDS + (cw + nt*16 + ln)*256 + (kb ^ swz));
    #pragma unroll
    for (int mt = 0; mt < 2; ++mt)
      #pragma unroll
      for (int nt = 0; nt < 4; ++nt)
        acc[mt][nt] = __builtin_amdgcn_mfma_f32_16x16x32_bf16(a[mt], b[nt], acc[mt][nt], 0, 0, 0);
  }
  float b1v[4];
  #pragma unroll
  for (int nt = 0; nt < 4; ++nt) b1v[nt] = b1[cw + nt*16 + ln];
  #pragma unroll
  for (int mt = 0; mt < 2; ++mt)
    #pragma unroll
    for (int q = 0; q < 4; ++q) {
      int m = m0 + rw + mt*16 + 4*lg + q;
      #pragma unroll
      for (int nt = 0; nt < 4; ++nt) {
        float x = acc[mt][nt][q] + b1v[nt];
        Hb[m*128 + cw + nt*16 + ln] = f2bf(silu_f(x));
      }
    }
}

// ---------- kAgg: branch-free masked row/col sums + X2 chunks 0-2 ----------
__global__ __launch_bounds__(128) void kAgg(const unsigned short* __restrict__ Hb,
    const unsigned char* __restrict__ mb, const int* __restrict__ flag,
    float* __restrict__ ra, unsigned short* __restrict__ X2)
{
  int p = blockIdx.x, b = blockIdx.y;
  int tid = threadIdx.x;
  int s = *flag;
  int half = tid >> 6;
  int t = tid & 63;
  float a0 = 0.f, a1 = 0.f;
  #pragma unroll 16
  for (int q = 0; q < NL; ++q) {
    int mi = half ? ((q*NL + p)*NB + b) : ((p*NL + q)*NB + b);
    float mv = (float)mb[mi*s];
    unsigned u = *(const unsigned*)(Hb + mi*128 + 2*t);
    a0 += mv * bf2f((unsigned short)(u & 0xffffu));
    a1 += mv * bf2f((unsigned short)(u >> 16));
  }
  a0 *= (1.0f/60.0f); a1 *= (1.0f/60.0f);
  int ix = p*NB + b;
  unsigned pk = ((unsigned)f2bf(a1) << 16) | (unsigned)f2bf(a0);
  if (half) {
    *(float2*)(ra + ix*128 + 2*t) = make_float2(a0, a1);
    *(unsigned*)(X2 + ix*384 + 128 + 2*t) = pk;
  } else {
    *(unsigned*)(X2 + ix*384 + 256 + 2*t) = pk;
    unsigned d = *(const unsigned*)(Hb + ((p*NL + p)*NB + b)*128 + 2*t);
    *(unsigned*)(X2 + ix*384 + 2*t) = d;
  }
}

// ---------- kDm: y<3 MFMA [Aj|Ai|Adg] = X2 @ Wd^T ; y==3: Abase/Dga ----------
__global__ __launch_bounds__(256) void kDm(const unsigned short* __restrict__ X2,
    const unsigned short* __restrict__ wd,
    const unsigned short* __restrict__ Hb, const unsigned char* __restrict__ mb,
    const int* __restrict__ flag, const float* __restrict__ ra,
    const float* __restrict__ w2, const float* __restrict__ b2,
    float* __restrict__ Aj, float* __restrict__ Ai, float* __restrict__ Adg,
    float* __restrict__ Ab, float* __restrict__ Dga)
{
  int tid = threadIdx.x;
  if (blockIdx.y == 3) {
    int b = blockIdx.x;
    __shared__ float aas[128], dgs[128];
    int e = tid & 127;
    if (tid < 128) {
      int s = *flag;
      float aa = 0.f, dg = 0.f;
      #pragma unroll 8
      for (int p = 0; p < NL; ++p) {
        aa += ra[(p*NB + b)*128 + e];
        int mi = (p*NL + p)*NB + b;
        dg += (float)mb[mi*s] * bf2f(Hb[mi*128 + e]);
      }
      aas[e] = aa * (1.0f/60.0f);
      dgs[e] = dg * (1.0f/60.0f);
    }
    __syncthreads();
    if (tid < 128) {
      float ab = b2[e];
      #pragma unroll 8
      for (int k = 0; k < 128; ++k) {
        int o = k*128 + e;
        ab += dgs[k]*w2[8*16384 + o] + aas[k]*(w2[11*16384 + o] + w2[14*16384 + o]);
      }
      Ab[b*128 + e] = ab;
    } else {
      float dga = 0.f;
      #pragma unroll 8
      for (int k = 0; k < 128; ++k)
        dga += dgs[k]*w2[7*16384 + k*128 + e];
      Dga[b*128 + e] = dga;
    }
    return;
  }
  if (blockIdx.x >= 12) return;

  __shared__ __align__(16) char ADS[64*256];
  __shared__ __align__(16) char BDS[128*256];
  int m0 = blockIdx.x * 64;
  int n0 = blockIdx.y * 128;

  int wave = tid >> 6, lane = tid & 63;
  int ln = lane & 15, lg = lane >> 4;
  int rw = (wave >> 1) * 32, cw = (wave & 1) * 64;
  int swzk = (ln & 7) << 4;
  f32x4 acc[2][4];
  #pragma unroll
  for (int mt = 0; mt < 2; ++mt)
    #pragma unroll
    for (int nt = 0; nt < 4; ++nt) acc[mt][nt] = (f32x4){0.f,0.f,0.f,0.f};

  for (int kc = 0; kc < 3; ++kc) {
    if (kc) __syncthreads();
    #pragma unroll
    for (int t = 0; t < 4; ++t) {
      int f = t*256 + tid;
      int r = f >> 4, c16 = f & 15;
      short8 v = *(const short8*)(X2 + (m0 + r)*384 + kc*128 + c16*8);
      *(short8*)(ADS + r*256 + ((c16*16) ^ ((r & 7) << 4))) = v;
    }
    #pragma unroll
    for (int t = 0; t < 8; ++t) {
      int f = t*256 + tid;
      int r = f >> 4, c16 = f & 15;
      short8 v = *(const short8*)(wd + (n0 + r)*384 + kc*128 + c16*8);
      *(short8*)(BDS + r*256 + ((c16*16) ^ ((r & 7) << 4))) = v;
    }
    __syncthreads();
    #pragma unroll
    for (int ks = 0; ks < 4; ++ks) {
      int kb = ks*64 + lg*16;
      short8 a[2], b[4];
      #pragma unroll
      for (int mt = 0; mt < 2; ++mt)
        a[mt] = *(const short8*)(ADS + (rw + mt*16 + ln)*256 + (kb ^ swzk));
      #pragma unroll
      for (int nt = 0; nt < 4; ++nt)
        b[nt] = *(const short8*)(BDS + (cw + nt*16 + ln)*256 + (kb ^ swzk));
      #pragma unroll
      for (int mt = 0; mt < 2; ++mt)
        #pragma unroll
        for (int nt = 0; nt < 4; ++nt)
          acc[mt][nt] = __builtin_amdgcn_mfma_f32_16x16x32_bf16(a[mt], b[nt], acc[mt][nt], 0, 0, 0);
    }
  }
  float* outp = (blockIdx.y == 0) ? Aj : (blockIdx.y == 1) ? Ai : Adg;
  #pragma unroll
  for (int mt = 0; mt < 2; ++mt)
    #pragma unroll
    for (int q = 0; q < 4; ++q) {
      int row = m0 + rw + mt*16 + 4*lg + q;
      #pragma unroll
      for (int nt = 0; nt < 4; ++nt)
        outp[row*128 + cw + nt*16 + ln] = acc[mt][nt][q];
    }
}

// ---------- kernel E (MFMA): out = Hd@W4 + Ht@W3 + additive ----------
// A restaged per K-half (16 KB) + BDS per half (32 KB) -> 48 KB LDS, 3 blocks/CU
__global__ __launch_bounds__(256) void kE(const unsigned short* __restrict__ Hb,
    const unsigned short* __restrict__ w34t,
    const float* __restrict__ Aj, const float* __restrict__ Ai,
    const float* __restrict__ Adg, const float* __restrict__ Ab,
    const float* __restrict__ Dga,
    float* __restrict__ out)
{
  __shared__ __align__(16) char ADS[64*256];
  __shared__ __align__(16) char BDS[128*256];
  int tid = threadIdx.x;
  int bi = blockIdx.x / 12;
  int j0 = (blockIdx.x % 12) * 4;
  int m0 = (bi*NL + j0) * NB;

  int wave = tid >> 6, lane = tid & 63;
  int ln = lane & 15, lg = lane >> 4;
  int rw = (wave >> 1) * 32, cw = (wave & 1) * 64;
  int swz = (ln & 7) << 4;
  f32x4 acc[2][4];
  #pragma unroll
  for (int mt = 0; mt < 2; ++mt)
    #pragma unroll
    for (int nt = 0; nt < 4; ++nt) acc[mt][nt] = (f32x4){0.f,0.f,0.f,0.f};

  #pragma unroll
  for (int half = 0; half < 2; ++half) {
    if (half) __syncthreads();     // protect buffer reuse
    // stage A half: half0 = Hd rows (contiguous), half1 = Ht rows
    #pragma unroll
    for (int t = 0; t < 4; ++t) {
      int f = t*256 + tid;
      int r = f >> 4, c16 = f & 15;
      int srcrow = (half == 0) ? (m0 + r) : (((j0 + (r >> 4))*NL + bi)*NB + (r & 15));
      short8 v = *(const short8*)(Hb + srcrow*128 + c16*8);
      *(short8*)(ADS + r*256 + ((c16*16) ^ ((r & 7) << 4))) = v;
    }
    // stage B half
    #pragma unroll
    for (int t = 0; t < 8; ++t) {
      int f = t*256 + tid;
      int r = f >> 4, c16 = f & 15;
      short8 v = *(const short8*)(w34t + r*256 + half*128 + c16*8);
      *(short8*)(BDS + r*256 + ((c16*16) ^ ((r & 7) << 4))) = v;
    }
    __syncthreads();
    #pragma unroll
    for (int ks = 0; ks < 4; ++ks) {
      int kb = ks*64 + lg*16;
      short8 a[2], b[4];
      #pragma unroll
      for (int mt = 0; mt < 2; ++mt)
        a[mt] = *(const short8*)(ADS + (rw + mt*16 + ln)*256 + (kb ^ swz));
      #pragma unroll
      for (int nt = 0; nt < 4; ++nt)
        b[nt] = *(const short8*)(BDS + (cw + nt*16 + ln)*256 + (kb ^ swz));
      #pragma unroll
      for (int mt = 0; mt < 2; ++mt)
        #pragma unroll
        for (int nt = 0; nt < 4; ++nt)
          acc[mt][nt] = __builtin_amdgcn_mfma_f32_16x16x32_bf16(a[mt], b[nt], acc[mt][nt], 0, 0, 0);
    }
  }

  #pragma unroll
  for (int mt = 0; mt < 2; ++mt) {
    int tb = rw + mt*16;
    int jj = tb >> 4;
    int j = j0 + jj;
    bool isdiag = (bi == j);
    #pragma unroll
    for (int q = 0; q < 4; ++q) {
      int b = 4*lg + q;
      int m = (bi*NL + j)*NB + b;
      #pragma unroll
      for (int nt = 0; nt < 4; ++nt) {
        int n = cw + nt*16 + ln;
        float add = Aj[(j*NB + b)*128 + n] + Ai[(bi*NB + b)*128 + n] + Ab[b*128 + n];
        if (isdiag) add += Adg[(bi*NB + b)*128 + n] + Dga[b*128 + n];
        out[m*128 + n] = acc[mt][nt][q] + add;
      }
    }
  }
}

extern "C" void kernel_launch(void* const* d_in, const int* in_sizes, int n_in,
                              void* d_out, int out_size, void* d_ws, size_t ws_size,
                              hipStream_t stream) {
  (void)in_sizes; (void)n_in; (void)out_size; (void)ws_size;
  const float* T      = (const float*)d_in[0];
  const unsigned char* mask = (const unsigned char*)d_in[1];
  const float* rmean  = (const float*)d_in[2];
  const float* rvar   = (const float*)d_in[3];
  const float* bw     = (const float*)d_in[4];
  const float* bb     = (const float*)d_in[5];
  const float* w1     = (const float*)d_in[6];
  const float* b1     = (const float*)d_in[7];
  const float* w2     = (const float*)d_in[8];
  const float* b2     = (const float*)d_in[9];
  float* ws  = (float*)d_ws;
  float* out = (float*)d_out;

  unsigned short* Hb   = (unsigned short*)(ws + HB_OFF);
  unsigned short* w34t = (unsigned short*)(ws + W34T_OFF);
  unsigned short* wd   = (unsigned short*)(ws + WD_OFF);
  unsigned short* X2   = (unsigned short*)(ws + X2_OFF);
  float* ra   = ws + RA_OFF;
  float* Aj   = ws + AJ_OFF;
  float* Ai   = ws + AI_OFF;
  float* Adg  = ws + AD_OFF;
  float* Ab   = ws + AB_OFF;
  float* Dga  = ws + DGA_OFF;
  int*   flag = (int*)(ws + FLAG_OFF);

  kA<<<621, 256, 0, stream>>>(T, rmean, rvar, bw, bb, w1, b1, w2, mask,
                              Hb, w34t, wd, flag);
  kAgg<<<dim3(NL, NB), 128, 0, stream>>>(Hb, mask, flag, ra, X2);
  kDm<<<dim3(16, 4), 256, 0, stream>>>(X2, wd, Hb, mask, flag, ra, w2, b2,
                                       Aj, Ai, Adg, Ab, Dga);
  kE<<<NROWS/64, 256, 0, stream>>>(Hb, w34t, Aj, Ai, Adg, Ab, Dga, out);
}